// Round 3
// baseline (549.168 us; speedup 1.0000x reference)
//
#include <hip/hip_runtime.h>
#include <hip/hip_fp16.h>
#include <stdint.h>

#define S_DIM 64
#define L_DIM 64
#define B_DIM 16
#define LB    1024      // L*B
#define DIN   1024
#define DA    512
#define M_TOT 65536     // S*LB

using f16x8 = __attribute__((ext_vector_type(8))) _Float16;
using f32x4 = __attribute__((ext_vector_type(4))) float;

typedef const __attribute__((address_space(1))) void* gas_ptr;
typedef __attribute__((address_space(3))) void* las_ptr;

__device__ __forceinline__ void load_lds16(const void* g, void* l) {
    __builtin_amdgcn_global_load_lds((gas_ptr)g, (las_ptr)l, 16, 0, 0);
}

__device__ __forceinline__ float fast_tanh(float x) {
    return 1.0f - 2.0f / (__expf(2.0f * x) + 1.0f);
}

// ---------------- K0: convert Wc, Wq, query to fp16 in workspace -----------
__global__ void cvt_all(const float* __restrict__ Wc, const float* __restrict__ Wq,
                        const float* __restrict__ q,
                        _Float16* __restrict__ Wch, _Float16* __restrict__ Wqh,
                        _Float16* __restrict__ Qh) {
    int i = blockIdx.x * 256 + threadIdx.x;
    if (i < DA * DIN)            Wch[i] = (_Float16)Wc[i];
    else if (i < 2 * DA * DIN)   Wqh[i - DA * DIN] = (_Float16)Wq[i - DA * DIN];
    else                         Qh[i - 2 * DA * DIN] = (_Float16)q[i - 2 * DA * DIN];
}

// ---------------- K1: qp'[lb][n] = query@Wq^T + bq + bc --------------------
__global__ __launch_bounds__(256) void qp_gemm(
    const _Float16* __restrict__ Qh,    // [LB][DIN]
    const _Float16* __restrict__ Wqh,   // [DA][DIN]
    const float* __restrict__ bq, const float* __restrict__ bc,
    float* __restrict__ qp)             // [LB][DA]
{
    __shared__ __align__(16) _Float16 lA[64 * 64];
    __shared__ __align__(16) _Float16 lB[64 * 64];
    const int t = threadIdx.x;
    const int w = t >> 6, lane = t & 63;
    const int quad = lane >> 4, m16 = lane & 15;
    const int n0 = blockIdx.x * 64, lb0 = blockIdx.y * 64;

    f32x4 acc[4] = {};

    for (int kt = 0; kt < DIN / 64; ++kt) {
#pragma unroll
        for (int i = 0; i < 2; ++i) {
            int c = (w * 2 + i) * 64 + lane;
            int row = c >> 3;
            int kc = (c & 7) ^ (row & 7);
            load_lds16(Qh  + (size_t)(lb0 + row) * DIN + kt * 64 + kc * 8, (char*)lA + (size_t)c * 16);
            load_lds16(Wqh + (size_t)(n0  + row) * DIN + kt * 64 + kc * 8, (char*)lB + (size_t)c * 16);
        }
        __syncthreads();
#pragma unroll
        for (int kk = 0; kk < 64; kk += 32) {
            int cq = (kk >> 3) + quad;
            int ar = 16 * w + m16;
            f16x8 a = *(const f16x8*)((const char*)lA + ar * 128 + ((cq ^ (ar & 7)) * 16));
#pragma unroll
            for (int j = 0; j < 4; ++j) {
                int br = 16 * j + m16;
                f16x8 b = *(const f16x8*)((const char*)lB + br * 128 + ((cq ^ (br & 7)) * 16));
                acc[j] = __builtin_amdgcn_mfma_f32_16x16x32_f16(a, b, acc[j], 0, 0, 0);
            }
        }
        __syncthreads();
    }
#pragma unroll
    for (int j = 0; j < 4; ++j) {
        int n = n0 + 16 * j + m16;
        float bias = bq[n] + bc[n];
#pragma unroll
        for (int r = 0; r < 4; ++r) {
            int lb = lb0 + 16 * w + quad * 4 + r;
            qp[(size_t)lb * DA + n] = acc[j][r] + bias;
        }
    }
}

// ---------------- K2: score GEMM, fp32 A with post-barrier reg prefetch ----
// 128x128 tile, 256 threads / 4 waves (2m x 2n), BK=64, K=1024.
// Per iter: [barrier1] -> B lds-DMA + A cvt/ds_write -> [barrier2] ->
//           A(kt+1) f32 prefetch (in flight during MFMA) -> MFMA(kt).
// Epilogue: tanh(cp+qp')*v reduced over n -> per-nq partial (no atomics).
__global__ __launch_bounds__(256) void score_gemm3(
    const float* __restrict__ ctx,      // [M_TOT][DIN] fp32
    const _Float16* __restrict__ Wch,   // [DA][DIN]
    const float* __restrict__ qp,       // [LB][DA]
    const float* __restrict__ v,        // [DA]
    float* __restrict__ sc4)            // [4][M_TOT] partials
{
    __shared__ __align__(16) _Float16 lA[128 * 64];   // 16 KB
    __shared__ __align__(16) _Float16 lB[128 * 64];   // 16 KB
    __shared__ float lP[2][128];

    const int t = threadIdx.x;
    const int w = t >> 6, lane = t & 63;
    const int quad = lane >> 4, m16 = lane & 15;
    const int wm = w & 1, wn = w >> 1;

    int bid = blockIdx.x;
    int xcd = bid & 7;
    int j2 = bid >> 3;
    int nq = j2 & 3;
    int mb = ((j2 >> 2) << 3) | xcd;
    const int m0 = mb * 128;
    const int n0 = nq * 128;

    f32x4 acc[4][4] = {};

    const int arow = t >> 1;                          // 0..127
    const int acol = t & 1;                           // which 32-float half
    const float* gA = ctx + (size_t)(m0 + arow) * DIN + acol * 32;

    // prologue: load A tile 0 into regs
    f32x4 fA[8];
#pragma unroll
    for (int qd = 0; qd < 8; ++qd) fA[qd] = *(const f32x4*)(gA + qd * 4);

#pragma unroll 1
    for (int kt = 0; kt < DIN / 64; ++kt) {
        if (kt) __syncthreads();                      // waves done reading tile kt-1
        // B: fire-and-forget lds-DMA (overlaps the A cvt/ds_write below)
#pragma unroll
        for (int i = 0; i < 4; ++i) {
            int c = (w * 4 + i) * 64 + lane;
            int row = c >> 3;
            int kc = (c & 7) ^ (row & 7);
            load_lds16(Wch + (size_t)(n0 + row) * DIN + kt * 64 + kc * 8,
                       (char*)lB + (size_t)c * 16);
        }
        // A: cvt regs -> swizzled ds_write_b128
#pragma unroll
        for (int q2 = 0; q2 < 4; ++q2) {
            f16x8 h = {(_Float16)fA[2*q2][0], (_Float16)fA[2*q2][1],
                       (_Float16)fA[2*q2][2], (_Float16)fA[2*q2][3],
                       (_Float16)fA[2*q2+1][0], (_Float16)fA[2*q2+1][1],
                       (_Float16)fA[2*q2+1][2], (_Float16)fA[2*q2+1][3]};
            int c = acol * 4 + q2;
            *(f16x8*)((char*)lA + arow * 128 + ((c ^ (arow & 7)) * 16)) = h;
        }
        __syncthreads();                              // tile kt visible
        // prefetch A tile kt+1 (drained only at next iter's first barrier)
        if (kt < DIN / 64 - 1) {
            const float* p = gA + (kt + 1) * 64;
#pragma unroll
            for (int qd = 0; qd < 8; ++qd) fA[qd] = *(const f32x4*)(p + qd * 4);
        }
        // MFMA on tile kt
#pragma unroll
        for (int kk = 0; kk < 64; kk += 32) {
            int cq = (kk >> 3) + quad;
            f16x8 a[4], b[4];
#pragma unroll
            for (int i = 0; i < 4; ++i) {
                int ar = wm * 64 + 16 * i + m16;
                a[i] = *(const f16x8*)((const char*)lA + ar * 128 + ((cq ^ (ar & 7)) * 16));
            }
#pragma unroll
            for (int j = 0; j < 4; ++j) {
                int br = wn * 64 + 16 * j + m16;
                b[j] = *(const f16x8*)((const char*)lB + br * 128 + ((cq ^ (br & 7)) * 16));
            }
#pragma unroll
            for (int i = 0; i < 4; ++i)
#pragma unroll
                for (int j = 0; j < 4; ++j)
                    acc[i][j] = __builtin_amdgcn_mfma_f32_16x16x32_f16(a[i], b[j], acc[i][j], 0, 0, 0);
        }
    }

    // ---- epilogue ----
    float vv[4];
    int nn[4];
#pragma unroll
    for (int j = 0; j < 4; ++j) { nn[j] = n0 + wn * 64 + 16 * j + m16; vv[j] = v[nn[j]]; }

    float part[16];
#pragma unroll
    for (int i = 0; i < 4; ++i) {
#pragma unroll
        for (int r = 0; r < 4; ++r) {
            int gm = m0 + wm * 64 + 16 * i + quad * 4 + r;
            int lb = gm & (LB - 1);
            float s = 0.f;
#pragma unroll
            for (int j = 0; j < 4; ++j) {
                float x = acc[i][j][r] + qp[(size_t)lb * DA + nn[j]];
                s += fast_tanh(x) * vv[j];
            }
            part[i * 4 + r] = s;
        }
    }
#pragma unroll
    for (int off = 1; off < 16; off <<= 1) {
#pragma unroll
        for (int k = 0; k < 16; ++k) part[k] += __shfl_xor(part[k], off, 64);
    }
    if (m16 == 0) {
#pragma unroll
        for (int k = 0; k < 16; ++k) {
            int row_local = wm * 64 + 16 * (k >> 2) + quad * 4 + (k & 3);
            lP[wn][row_local] = part[k];
        }
    }
    __syncthreads();
    if (t < 128) {
        float s = lP[0][t] + lP[1][t];
        sc4[(size_t)nq * M_TOT + m0 + t] = s;
    }
}

// ---------------- K3: fused softmax (over s) + weighted sum ----------------
// One block per lb. Wave 0: sum 4 partials, mask, 64-wide softmax, write
// alpha. Then all 256 threads: out[lb][d] = sum_s alpha[s]*ctx[s][lb][d].
__global__ __launch_bounds__(256) void softmax_ws(
    const float* __restrict__ sc4, const int* __restrict__ mask,
    const float* __restrict__ ctx,
    float* __restrict__ alpha_out, float* __restrict__ attn_out) {
    __shared__ float lAl[S_DIM];
    const int lb = blockIdx.x;
    const int t = threadIdx.x;
    if (t < S_DIM) {
        int s = t;
        int idx = s * LB + lb;
        float x = sc4[idx] + sc4[M_TOT + idx] + sc4[2 * M_TOT + idx] + sc4[3 * M_TOT + idx];
        if (mask[idx] == 0) x = -1e9f;
        float mx = x;
#pragma unroll
        for (int off = 1; off < 64; off <<= 1) mx = fmaxf(mx, __shfl_xor(mx, off, 64));
        float e = __expf(x - mx);
        float sum = e;
#pragma unroll
        for (int off = 1; off < 64; off <<= 1) sum += __shfl_xor(sum, off, 64);
        float a = e / sum;
        alpha_out[idx] = a;
        lAl[s] = a;
    }
    __syncthreads();
    f32x4 acc = {0.f, 0.f, 0.f, 0.f};
    const float* base = ctx + (size_t)lb * DIN + t * 4;
#pragma unroll 4
    for (int s = 0; s < S_DIM; ++s) {
        float a = lAl[s];
        f32x4 c = *(const f32x4*)(base + (size_t)s * LB * DIN);
        acc += a * c;
    }
    *(f32x4*)(attn_out + (size_t)lb * DIN + t * 4) = acc;
}

extern "C" void kernel_launch(void* const* d_in, const int* in_sizes, int n_in,
                              void* d_out, int out_size, void* d_ws, size_t ws_size,
                              hipStream_t stream) {
    (void)in_sizes; (void)n_in; (void)out_size; (void)ws_size;
    const float* ctx   = (const float*)d_in[0];
    const float* query = (const float*)d_in[1];
    const int*   mask  = (const int*)d_in[2];
    const float* Wc    = (const float*)d_in[3];
    const float* bc    = (const float*)d_in[4];
    const float* Wq    = (const float*)d_in[5];
    const float* bq    = (const float*)d_in[6];
    const float* v     = (const float*)d_in[7];

    float* out_attn  = (float*)d_out;                       // [LB][DIN]
    float* out_alpha = (float*)d_out + (size_t)LB * DIN;    // [S][LB]

    char* ws = (char*)d_ws;
    _Float16* Wch = (_Float16*)(ws);                        // 1 MB
    _Float16* Wqh = (_Float16*)(ws + (1 << 20));            // 1 MB
    _Float16* Qh  = (_Float16*)(ws + (2 << 20));            // 2 MB
    float*    qp  = (float*)(ws + (4 << 20));               // 2 MB
    float*    sc4 = (float*)(ws + (6 << 20));               // 1 MB

    cvt_all<<<(2 * DA * DIN + LB * DIN) / 256, 256, 0, stream>>>(Wc, Wq, query, Wch, Wqh, Qh);
    qp_gemm<<<dim3(DA / 64, LB / 64), 256, 0, stream>>>(Qh, Wqh, bq, bc, qp);
    score_gemm3<<<2048, 256, 0, stream>>>(ctx, Wch, qp, v, sc4);
    softmax_ws<<<LB, 256, 0, stream>>>(sc4, mask, ctx, out_alpha, out_attn);
}